// Round 2
// baseline (697.686 us; speedup 1.0000x reference)
//
#include <hip/hip_runtime.h>
#include <hip/hip_bf16.h>
#include <cstddef>

// ---------------------------------------------------------------------------
// GNN layer (RED-GNN style), MI355X — round 2.
// Change vs round 1: replace 64M fp32 atomicAdds (256 MB of L2 RMW write
// traffic, the measured bottleneck) with a CSR-gather segment sum:
//   edge_kernel: slot[e]=atomicAdd(cnt[obj],1)  (1M int atomics only)
//   scan:        offs = exclusive_scan(cnt)     (3-pass, parallel)
//   scatter:     eidx[offs[obj]+slot] = e
//   agg+matmul:  per-node wave gathers its message rows, sums in registers,
//                and applies W_h in the same kernel (deletes agg buffer,
//                its memset, and the 4th matmul launch).
// ---------------------------------------------------------------------------

// Y[row] = X[row] @ W (+ bias). W staged in LDS. block=256 = 4 rows x 64 cols.
__global__ void matmul64_kernel(const float* __restrict__ X,
                                const float* __restrict__ W,
                                const float* __restrict__ bias,
                                float* __restrict__ Y, int nrows) {
    __shared__ float Wl[64][64];
    int tid = threadIdx.x;
    for (int i = tid; i < 4096; i += 256) Wl[i >> 6][i & 63] = W[i];
    __syncthreads();
    int col = tid & 63;
    int r4  = tid >> 6;
    for (long row = (long)blockIdx.x * 4 + r4; row < nrows;
         row += (long)gridDim.x * 4) {
        float xv  = X[row * 64 + col];
        float acc = bias ? bias[col] : 0.0f;
#pragma unroll
        for (int k = 0; k < 64; ++k)
            acc = fmaf(__shfl(xv, k, 64), Wl[k][col], acc);
        Y[row * 64 + col] = acc;
    }
}

// B_r = rela@Wr ; C_q = rela[q_rel]@Wqr + Wqr_b.
__global__ void rel_precompute_kernel(const float* __restrict__ rela,
                                      const float* __restrict__ Wr,
                                      const float* __restrict__ Wqr,
                                      const float* __restrict__ Wqr_b,
                                      const int* __restrict__ q_rel,
                                      float* __restrict__ Br,
                                      float* __restrict__ Cq,
                                      int nrel, int nq) {
    __shared__ float W1[64][64];
    __shared__ float W2[64][64];
    int tid = threadIdx.x;
    for (int i = tid; i < 4096; i += 256) {
        W1[i >> 6][i & 63] = Wr[i];
        W2[i >> 6][i & 63] = Wqr[i];
    }
    __syncthreads();
    int col = tid & 63;
    int r4  = tid >> 6;
    int total = nrel + nq;
    for (int row = blockIdx.x * 4 + r4; row < total; row += gridDim.x * 4) {
        if (row < nrel) {
            float xv  = rela[(size_t)row * 64 + col];
            float acc = 0.0f;
#pragma unroll
            for (int k = 0; k < 64; ++k)
                acc = fmaf(__shfl(xv, k, 64), W1[k][col], acc);
            Br[(size_t)row * 64 + col] = acc;
        } else {
            int q  = row - nrel;
            int rr = q_rel[q];
            float xv  = rela[(size_t)rr * 64 + col];
            float acc = Wqr_b[col];
#pragma unroll
            for (int k = 0; k < 64; ++k)
                acc = fmaf(__shfl(xv, k, 64), W2[k][col], acc);
            Cq[(size_t)q * 64 + col] = acc;
        }
    }
}

// One wave per edge; lane = feature dim. No fp32 atomics — histogram only.
__global__ void edge_kernel(const int* __restrict__ edges,
                            const float* __restrict__ hidden,
                            const float* __restrict__ rela,
                            const float* __restrict__ hsWs,
                            const float* __restrict__ Br,
                            const float* __restrict__ Cq,
                            const float* __restrict__ w_alpha_w,
                            const float* __restrict__ w_alpha_b,
                            int* __restrict__ cnt,
                            int* __restrict__ slot,
                            int* __restrict__ obj_i,
                            float* __restrict__ out_alpha,
                            float* __restrict__ out_message,
                            float* __restrict__ out_obj,
                            float* __restrict__ out_alpha_temp,
                            int nedge) {
    int lane = threadIdx.x & 63;
    long e = (long)blockIdx.x * 4 + (threadIdx.x >> 6);
    if (e >= nedge) return;

    const int* ed = edges + e * 6;
    int r_idx = ed[0];
    int rel   = ed[2];
    int sub   = ed[4];
    int obj   = ed[5];

    float attn = hsWs[(size_t)sub * 64 + lane]
               + Br[(size_t)rel * 64 + lane]
               + Cq[(size_t)r_idx * 64 + lane];
    attn = fmaxf(attn, 0.0f);

    float dot = attn * w_alpha_w[lane];
#pragma unroll
    for (int m = 1; m < 64; m <<= 1) dot += __shfl_xor(dot, m, 64);
    float at    = dot + w_alpha_b[0];
    float alpha = 1.0f / (1.0f + __expf(-at));

    float msg = alpha * (hidden[(size_t)sub * 64 + lane]
                       + rela[(size_t)rel * 64 + lane]);

    out_message[e * 64 + lane] = msg;

    if (lane == 0) {
        slot[e]           = atomicAdd(&cnt[obj], 1);
        obj_i[e]          = obj;
        out_alpha[e]      = alpha;
        out_obj[e]        = (float)obj;
        out_alpha_temp[e] = at;
    }
}

// ---- 3-pass exclusive scan over cnt[n] -> offs[n], chunk = 1024 ----

__global__ void scan_reduce_kernel(const int* __restrict__ cnt,
                                   int* __restrict__ bsum, int n) {
    int i = blockIdx.x * 1024 + threadIdx.x;
    int v = (i < n) ? cnt[i] : 0;
    int lane = threadIdx.x & 63, w = threadIdx.x >> 6;
#pragma unroll
    for (int m = 1; m < 64; m <<= 1) v += __shfl_xor(v, m, 64);
    __shared__ int ws[16];
    if (lane == 0) ws[w] = v;
    __syncthreads();
    if (threadIdx.x == 0) {
        int s = 0;
#pragma unroll
        for (int k = 0; k < 16; ++k) s += ws[k];
        bsum[blockIdx.x] = s;
    }
}

// single block: in-place exclusive scan of bsum[nb], nb <= 1024
__global__ void scan_top_kernel(int* __restrict__ bsum, int nb) {
    int tid = threadIdx.x;
    int lane = tid & 63, w = tid >> 6;
    int v = (tid < nb) ? bsum[tid] : 0;
    int ins = v;
#pragma unroll
    for (int off = 1; off < 64; off <<= 1) {
        int t = __shfl_up(ins, off, 64);
        if (lane >= off) ins += t;
    }
    __shared__ int ws[16];
    __shared__ int wo[16];
    if (lane == 63) ws[w] = ins;
    __syncthreads();
    if (tid == 0) {
        int s = 0;
        for (int k = 0; k < 16; ++k) { wo[k] = s; s += ws[k]; }
    }
    __syncthreads();
    if (tid < nb) bsum[tid] = wo[w] + ins - v;   // exclusive
}

__global__ void scan_apply_kernel(const int* __restrict__ cnt,
                                  const int* __restrict__ boffs,
                                  int* __restrict__ offs, int n) {
    int i = blockIdx.x * 1024 + threadIdx.x;
    int lane = threadIdx.x & 63, w = threadIdx.x >> 6;
    int v = (i < n) ? cnt[i] : 0;
    int ins = v;
#pragma unroll
    for (int off = 1; off < 64; off <<= 1) {
        int t = __shfl_up(ins, off, 64);
        if (lane >= off) ins += t;
    }
    __shared__ int ws[16];
    __shared__ int wo[16];
    if (lane == 63) ws[w] = ins;
    __syncthreads();
    if (threadIdx.x == 0) {
        int s = 0;
        for (int k = 0; k < 16; ++k) { wo[k] = s; s += ws[k]; }
    }
    __syncthreads();
    if (i < n) offs[i] = boffs[blockIdx.x] + wo[w] + ins - v;
}

__global__ void scatter_kernel(const int* __restrict__ obj_i,
                               const int* __restrict__ slot,
                               const int* __restrict__ offs,
                               int* __restrict__ eidx, int nedge) {
    int e = blockIdx.x * 256 + threadIdx.x;
    if (e >= nedge) return;
    eidx[offs[obj_i[e]] + slot[e]] = e;
}

// Per-node wave: sum incoming message rows, then hidden_new = agg @ W_h.
__global__ void agg_matmul_kernel(const float* __restrict__ message,
                                  const int* __restrict__ eidx,
                                  const int* __restrict__ offs,
                                  const int* __restrict__ cnt,
                                  const float* __restrict__ Wh,
                                  float* __restrict__ hidden_new,
                                  int nnode) {
    __shared__ float Wl[64][64];
    int tid = threadIdx.x;
    for (int i = tid; i < 4096; i += 256) Wl[i >> 6][i & 63] = Wh[i];
    __syncthreads();
    int lane = tid & 63;
    int r4   = tid >> 6;
    for (long node = (long)blockIdx.x * 4 + r4; node < nnode;
         node += (long)gridDim.x * 4) {
        int beg = offs[node];
        int num = cnt[node];
        float acc = 0.0f;
        for (int j = 0; j < num; ++j) {
            int e = eidx[beg + j];
            acc += message[(size_t)e * 64 + lane];
        }
        float out = 0.0f;
#pragma unroll
        for (int k = 0; k < 64; ++k)
            out = fmaf(__shfl(acc, k, 64), Wl[k][lane], out);
        hidden_new[node * 64 + lane] = out;
    }
}

extern "C" void kernel_launch(void* const* d_in, const int* in_sizes, int n_in,
                              void* d_out, int out_size, void* d_ws, size_t ws_size,
                              hipStream_t stream) {
    const int*   q_rel     = (const int*)d_in[1];
    const float* hidden    = (const float*)d_in[2];
    const int*   edges     = (const int*)d_in[3];
    const float* rela      = (const float*)d_in[5];
    const float* Ws        = (const float*)d_in[6];
    const float* Wr        = (const float*)d_in[7];
    const float* Wqr       = (const float*)d_in[8];
    const float* Wqr_b     = (const float*)d_in[9];
    const float* w_alpha_w = (const float*)d_in[10];
    const float* w_alpha_b = (const float*)d_in[11];
    const float* W_h       = (const float*)d_in[12];

    const int n_node = in_sizes[2] / 64;    // 100000
    const int n_edge = in_sizes[3] / 6;     // 1000000
    const int n_rel  = in_sizes[5] / 64;    // 401
    const int n_q    = in_sizes[1];         // 256

    // Output layout (all fp32, return order).
    float* out            = (float*)d_out;
    float* out_hidden_new = out;
    float* out_alpha      = out + (size_t)n_node * 64;
    float* out_message    = out_alpha + n_edge;
    float* out_obj        = out_message + (size_t)n_edge * 64;
    float* out_alpha_temp = out_obj + n_edge;

    // Workspace layout.
    float* hsWs = (float*)d_ws;                            // n_node*64 f32
    float* Br   = hsWs + (size_t)n_node * 64;              // n_rel*64
    float* Cq   = Br + (size_t)n_rel * 64;                 // n_q*64
    int*   cnt  = (int*)(Cq + (size_t)n_q * 64);           // n_node
    int*   offs = cnt + n_node;                            // n_node
    int*   slot = offs + n_node;                           // n_edge
    int*   obj_i= slot + n_edge;                           // n_edge
    int*   eidx = obj_i + n_edge;                          // n_edge
    int*   bsum = eidx + n_edge;                           // ~128

    const int nb = (n_node + 1023) / 1024;                 // scan blocks (98)

    hipMemsetAsync(cnt, 0, (size_t)n_node * sizeof(int), stream);

    // 1) hsWs = hidden @ Ws   (grid capped: W loaded into LDS 2048x not 25000x)
    matmul64_kernel<<<2048, 256, 0, stream>>>(hidden, Ws, nullptr, hsWs, n_node);

    // 2) B_r, C_q
    {
        int grid = (n_rel + n_q + 3) / 4;
        rel_precompute_kernel<<<grid, 256, 0, stream>>>(rela, Wr, Wqr, Wqr_b,
                                                        q_rel, Br, Cq, n_rel, n_q);
    }

    // 3) per-edge: attn, alpha, message + histogram(slot)
    {
        int grid = (n_edge + 3) / 4;
        edge_kernel<<<grid, 256, 0, stream>>>(edges, hidden, rela, hsWs, Br, Cq,
                                              w_alpha_w, w_alpha_b,
                                              cnt, slot, obj_i,
                                              out_alpha, out_message, out_obj,
                                              out_alpha_temp, n_edge);
    }

    // 4) offs = exclusive_scan(cnt)
    scan_reduce_kernel<<<nb, 1024, 0, stream>>>(cnt, bsum, n_node);
    scan_top_kernel<<<1, 1024, 0, stream>>>(bsum, nb);
    scan_apply_kernel<<<nb, 1024, 0, stream>>>(cnt, bsum, offs, n_node);

    // 5) eidx CSR scatter
    scatter_kernel<<<(n_edge + 255) / 256, 256, 0, stream>>>(obj_i, slot, offs,
                                                             eidx, n_edge);

    // 6) hidden_new = segment_sum(message, obj) @ W_h  (fused)
    agg_matmul_kernel<<<2048, 256, 0, stream>>>(out_message, eidx, offs, cnt,
                                                W_h, out_hidden_new, n_node);
}

// Round 3
// 505.247 us; speedup vs baseline: 1.3809x; 1.3809x over previous
//
#include <hip/hip_runtime.h>
#include <hip/hip_bf16.h>
#include <cstddef>

// ---------------------------------------------------------------------------
// GNN layer (RED-GNN style), MI355X — round 3.
// vs round 2 (698 us, agg latency-bound at 0.5 TB/s):
//  * edge_kernel stores the 256 MB message output with NON-TEMPORAL stores so
//    the gather tables (hidden, hsWs, edges, alpha ~100 MB) stay L3-resident.
//  * agg recomputes msg = alpha*(hidden[sub]+rela[rel]) from L3-resident
//    tables (12 B metadata/edge) instead of gathering 256 B rows from the
//    uncacheable message buffer; 8-wide MLP via lane-split metadata loads +
//    shuffle broadcast, alpha=0 masking for tails (branch-free).
// ---------------------------------------------------------------------------

#define NT_STORE(p, v) __builtin_nontemporal_store((v), (p))

// Y[row] = X[row] @ W. W staged in LDS. block=256 = 4 rows x 64 cols.
__global__ void matmul64_kernel(const float* __restrict__ X,
                                const float* __restrict__ W,
                                float* __restrict__ Y, int nrows) {
    __shared__ float Wl[64][64];
    int tid = threadIdx.x;
    for (int i = tid; i < 4096; i += 256) Wl[i >> 6][i & 63] = W[i];
    __syncthreads();
    int col = tid & 63;
    int r4  = tid >> 6;
    for (long row = (long)blockIdx.x * 4 + r4; row < nrows;
         row += (long)gridDim.x * 4) {
        float xv  = X[row * 64 + col];
        float acc = 0.0f;
#pragma unroll
        for (int k = 0; k < 64; ++k)
            acc = fmaf(__shfl(xv, k, 64), Wl[k][col], acc);
        Y[row * 64 + col] = acc;
    }
}

// B_r = rela@Wr ; C_q = rela[q_rel]@Wqr + Wqr_b.
__global__ void rel_precompute_kernel(const float* __restrict__ rela,
                                      const float* __restrict__ Wr,
                                      const float* __restrict__ Wqr,
                                      const float* __restrict__ Wqr_b,
                                      const int* __restrict__ q_rel,
                                      float* __restrict__ Br,
                                      float* __restrict__ Cq,
                                      int nrel, int nq) {
    __shared__ float W1[64][64];
    __shared__ float W2[64][64];
    int tid = threadIdx.x;
    for (int i = tid; i < 4096; i += 256) {
        W1[i >> 6][i & 63] = Wr[i];
        W2[i >> 6][i & 63] = Wqr[i];
    }
    __syncthreads();
    int col = tid & 63;
    int r4  = tid >> 6;
    int total = nrel + nq;
    for (int row = blockIdx.x * 4 + r4; row < total; row += gridDim.x * 4) {
        if (row < nrel) {
            float xv  = rela[(size_t)row * 64 + col];
            float acc = 0.0f;
#pragma unroll
            for (int k = 0; k < 64; ++k)
                acc = fmaf(__shfl(xv, k, 64), W1[k][col], acc);
            Br[(size_t)row * 64 + col] = acc;
        } else {
            int q  = row - nrel;
            int rr = q_rel[q];
            float xv  = rela[(size_t)rr * 64 + col];
            float acc = Wqr_b[col];
#pragma unroll
            for (int k = 0; k < 64; ++k)
                acc = fmaf(__shfl(xv, k, 64), W2[k][col], acc);
            Cq[(size_t)q * 64 + col] = acc;
        }
    }
}

// One wave per edge; lane = feature dim. NT stores for the big message write.
__global__ void edge_kernel(const int* __restrict__ edges,
                            const float* __restrict__ hidden,
                            const float* __restrict__ rela,
                            const float* __restrict__ hsWs,
                            const float* __restrict__ Br,
                            const float* __restrict__ Cq,
                            const float* __restrict__ w_alpha_w,
                            const float* __restrict__ w_alpha_b,
                            int* __restrict__ cnt,
                            int* __restrict__ slot,
                            int* __restrict__ obj_i,
                            float* __restrict__ out_alpha,
                            float* __restrict__ out_message,
                            float* __restrict__ out_obj,
                            float* __restrict__ out_alpha_temp,
                            int nedge) {
    int lane = threadIdx.x & 63;
    long e = (long)blockIdx.x * 4 + (threadIdx.x >> 6);
    if (e >= nedge) return;

    const int* ed = edges + e * 6;
    int r_idx = ed[0];
    int rel   = ed[2];
    int sub   = ed[4];
    int obj   = ed[5];

    float attn = hsWs[(size_t)sub * 64 + lane]
               + Br[(size_t)rel * 64 + lane]
               + Cq[(size_t)r_idx * 64 + lane];
    attn = fmaxf(attn, 0.0f);

    float dot = attn * w_alpha_w[lane];
#pragma unroll
    for (int m = 1; m < 64; m <<= 1) dot += __shfl_xor(dot, m, 64);
    float at    = dot + w_alpha_b[0];
    float alpha = 1.0f / (1.0f + __expf(-at));

    float msg = alpha * (hidden[(size_t)sub * 64 + lane]
                       + rela[(size_t)rel * 64 + lane]);

    NT_STORE(&out_message[e * 64 + lane], msg);

    if (lane == 0) {
        slot[e]  = atomicAdd(&cnt[obj], 1);
        obj_i[e] = obj;
        out_alpha[e] = alpha;                 // re-read by agg: keep cacheable
        NT_STORE(&out_obj[e], (float)obj);
        NT_STORE(&out_alpha_temp[e], at);
    }
}

// ---- 3-pass exclusive scan over cnt[n] -> offs[n], chunk = 1024 ----

__global__ void scan_reduce_kernel(const int* __restrict__ cnt,
                                   int* __restrict__ bsum, int n) {
    int i = blockIdx.x * 1024 + threadIdx.x;
    int v = (i < n) ? cnt[i] : 0;
    int lane = threadIdx.x & 63, w = threadIdx.x >> 6;
#pragma unroll
    for (int m = 1; m < 64; m <<= 1) v += __shfl_xor(v, m, 64);
    __shared__ int ws[16];
    if (lane == 0) ws[w] = v;
    __syncthreads();
    if (threadIdx.x == 0) {
        int s = 0;
#pragma unroll
        for (int k = 0; k < 16; ++k) s += ws[k];
        bsum[blockIdx.x] = s;
    }
}

__global__ void scan_top_kernel(int* __restrict__ bsum, int nb) {
    int tid = threadIdx.x;
    int lane = tid & 63, w = tid >> 6;
    int v = (tid < nb) ? bsum[tid] : 0;
    int ins = v;
#pragma unroll
    for (int off = 1; off < 64; off <<= 1) {
        int t = __shfl_up(ins, off, 64);
        if (lane >= off) ins += t;
    }
    __shared__ int ws[16];
    __shared__ int wo[16];
    if (lane == 63) ws[w] = ins;
    __syncthreads();
    if (tid == 0) {
        int s = 0;
        for (int k = 0; k < 16; ++k) { wo[k] = s; s += ws[k]; }
    }
    __syncthreads();
    if (tid < nb) bsum[tid] = wo[w] + ins - v;   // exclusive
}

__global__ void scan_apply_kernel(const int* __restrict__ cnt,
                                  const int* __restrict__ boffs,
                                  int* __restrict__ offs, int n) {
    int i = blockIdx.x * 1024 + threadIdx.x;
    int lane = threadIdx.x & 63, w = threadIdx.x >> 6;
    int v = (i < n) ? cnt[i] : 0;
    int ins = v;
#pragma unroll
    for (int off = 1; off < 64; off <<= 1) {
        int t = __shfl_up(ins, off, 64);
        if (lane >= off) ins += t;
    }
    __shared__ int ws[16];
    __shared__ int wo[16];
    if (lane == 63) ws[w] = ins;
    __syncthreads();
    if (threadIdx.x == 0) {
        int s = 0;
        for (int k = 0; k < 16; ++k) { wo[k] = s; s += ws[k]; }
    }
    __syncthreads();
    if (i < n) offs[i] = boffs[blockIdx.x] + wo[w] + ins - v;
}

__global__ void scatter_kernel(const int* __restrict__ obj_i,
                               const int* __restrict__ slot,
                               const int* __restrict__ offs,
                               int* __restrict__ eidx, int nedge) {
    int e = blockIdx.x * 256 + threadIdx.x;
    if (e >= nedge) return;
    eidx[offs[obj_i[e]] + slot[e]] = e;
}

// Per-node wave: RECOMPUTE msg rows from L3-resident tables, 8-wide MLP.
__global__ void agg_matmul_kernel(const float* __restrict__ alpha,
                                  const int* __restrict__ edges,
                                  const float* __restrict__ hidden,
                                  const float* __restrict__ rela,
                                  const int* __restrict__ eidx,
                                  const int* __restrict__ offs,
                                  const int* __restrict__ cnt,
                                  const float* __restrict__ Wh,
                                  float* __restrict__ hidden_new,
                                  int nnode) {
    __shared__ float Wl[64][64];
    int tid = threadIdx.x;
    for (int i = tid; i < 4096; i += 256) Wl[i >> 6][i & 63] = Wh[i];
    __syncthreads();
    int lane = tid & 63;
    int r4   = tid >> 6;
    for (long node = (long)blockIdx.x * 4 + r4; node < nnode;
         node += (long)gridDim.x * 4) {
        int beg = offs[node];
        int num = cnt[node];
        float acc = 0.0f;
        for (int j0 = 0; j0 < num; j0 += 8) {
            int m = min(8, num - j0);
            int sb = 0, rl = 0;
            float al = 0.0f;                  // lanes >= m contribute 0
            if (lane < m) {
                int e = eidx[beg + j0 + lane];
                sb = edges[(size_t)e * 6 + 4];
                rl = edges[(size_t)e * 6 + 2];
                al = alpha[e];
            }
#pragma unroll
            for (int k = 0; k < 8; ++k) {
                int   sbk = __shfl(sb, k, 64);
                int   rlk = __shfl(rl, k, 64);
                float alk = __shfl(al, k, 64);
                float hv  = hidden[(size_t)sbk * 64 + lane];
                float rv  = rela[(size_t)rlk * 64 + lane];
                acc += alk * (hv + rv);       // alk==0 masks tail/garbage
            }
        }
        float outv = 0.0f;
#pragma unroll
        for (int k = 0; k < 64; ++k)
            outv = fmaf(__shfl(acc, k, 64), Wl[k][lane], outv);
        NT_STORE(&hidden_new[node * 64 + lane], outv);
    }
}

extern "C" void kernel_launch(void* const* d_in, const int* in_sizes, int n_in,
                              void* d_out, int out_size, void* d_ws, size_t ws_size,
                              hipStream_t stream) {
    const int*   q_rel     = (const int*)d_in[1];
    const float* hidden    = (const float*)d_in[2];
    const int*   edges     = (const int*)d_in[3];
    const float* rela      = (const float*)d_in[5];
    const float* Ws        = (const float*)d_in[6];
    const float* Wr        = (const float*)d_in[7];
    const float* Wqr       = (const float*)d_in[8];
    const float* Wqr_b     = (const float*)d_in[9];
    const float* w_alpha_w = (const float*)d_in[10];
    const float* w_alpha_b = (const float*)d_in[11];
    const float* W_h       = (const float*)d_in[12];

    const int n_node = in_sizes[2] / 64;    // 100000
    const int n_edge = in_sizes[3] / 6;     // 1000000
    const int n_rel  = in_sizes[5] / 64;    // 401
    const int n_q    = in_sizes[1];         // 256

    // Output layout (all fp32, return order).
    float* out            = (float*)d_out;
    float* out_hidden_new = out;
    float* out_alpha      = out + (size_t)n_node * 64;
    float* out_message    = out_alpha + n_edge;
    float* out_obj        = out_message + (size_t)n_edge * 64;
    float* out_alpha_temp = out_obj + n_edge;

    // Workspace layout (~38.6 MB).
    float* hsWs = (float*)d_ws;                            // n_node*64 f32
    float* Br   = hsWs + (size_t)n_node * 64;              // n_rel*64
    float* Cq   = Br + (size_t)n_rel * 64;                 // n_q*64
    int*   cnt  = (int*)(Cq + (size_t)n_q * 64);           // n_node
    int*   offs = cnt + n_node;                            // n_node
    int*   slot = offs + n_node;                           // n_edge
    int*   obj_i= slot + n_edge;                           // n_edge
    int*   eidx = obj_i + n_edge;                          // n_edge
    int*   bsum = eidx + n_edge;                           // ~128

    const int nb = (n_node + 1023) / 1024;                 // scan blocks (98)

    hipMemsetAsync(cnt, 0, (size_t)n_node * sizeof(int), stream);

    // 1) hsWs = hidden @ Ws
    matmul64_kernel<<<2048, 256, 0, stream>>>(hidden, Ws, hsWs, n_node);

    // 2) B_r, C_q
    {
        int grid = (n_rel + n_q + 3) / 4;
        rel_precompute_kernel<<<grid, 256, 0, stream>>>(rela, Wr, Wqr, Wqr_b,
                                                        q_rel, Br, Cq, n_rel, n_q);
    }

    // 3) per-edge: attn, alpha, message (NT) + histogram(slot)
    {
        int grid = (n_edge + 3) / 4;
        edge_kernel<<<grid, 256, 0, stream>>>(edges, hidden, rela, hsWs, Br, Cq,
                                              w_alpha_w, w_alpha_b,
                                              cnt, slot, obj_i,
                                              out_alpha, out_message, out_obj,
                                              out_alpha_temp, n_edge);
    }

    // 4) offs = exclusive_scan(cnt)
    scan_reduce_kernel<<<nb, 1024, 0, stream>>>(cnt, bsum, n_node);
    scan_top_kernel<<<1, 1024, 0, stream>>>(bsum, nb);
    scan_apply_kernel<<<nb, 1024, 0, stream>>>(cnt, bsum, offs, n_node);

    // 5) eidx CSR scatter
    scatter_kernel<<<(n_edge + 255) / 256, 256, 0, stream>>>(obj_i, slot, offs,
                                                             eidx, n_edge);

    // 6) hidden_new = segment_sum @ W_h, recomputed from L3-resident tables
    agg_matmul_kernel<<<4096, 256, 0, stream>>>(out_alpha, edges, hidden, rela,
                                                eidx, offs, cnt,
                                                W_h, out_hidden_new, n_node);
}

// Round 5
// 349.911 us; speedup vs baseline: 1.9939x; 1.4439x over previous
//
#include <hip/hip_runtime.h>
#include <hip/hip_bf16.h>
#include <cstddef>

// ---------------------------------------------------------------------------
// GNN layer (RED-GNN style), MI355X — round 4b (compile fix of round 4).
// vs round 3 (505 us; edge_kernel pinned at ~297 us, issue/latency-bound):
//  * edge_kernel: 4 edges per wave, 16 lanes x float4 per edge. All gathers
//    become dwordx4; one VMEM instruction serves 4 edges; reduce chain 6->4
//    steps shared by 4 edges; metadata via one coalesced 24-int load +
//    shuffle broadcast. ~4x fewer issued instructions per edge.
//  * agg_matmul: same float4/4-edge structure; metadata for 64 edges loaded
//    by all lanes in parallel (deep MLP), float4 gathers, xor-group reduce,
//    then the 64x64 matvec from shuffled float4 components.
//  * NT stores via clang ext_vector f32x4 (HIP float4 is a class type that
//    __builtin_nontemporal_store rejects).
// ---------------------------------------------------------------------------

typedef float f32x4 __attribute__((ext_vector_type(4)));

static __device__ __forceinline__ void nt_store4(float* p, float4 v) {
    f32x4 t = {v.x, v.y, v.z, v.w};
    __builtin_nontemporal_store(t, (f32x4*)p);
}
#define NT_STORE(p, v) __builtin_nontemporal_store((v), (p))

// Y[row] = X[row] @ W. W staged in LDS. block=256 = 4 rows x 64 cols.
__global__ void matmul64_kernel(const float* __restrict__ X,
                                const float* __restrict__ W,
                                float* __restrict__ Y, int nrows) {
    __shared__ float Wl[64][64];
    int tid = threadIdx.x;
    for (int i = tid; i < 4096; i += 256) Wl[i >> 6][i & 63] = W[i];
    __syncthreads();
    int col = tid & 63;
    int r4  = tid >> 6;
    for (long row = (long)blockIdx.x * 4 + r4; row < nrows;
         row += (long)gridDim.x * 4) {
        float xv  = X[row * 64 + col];
        float acc = 0.0f;
#pragma unroll
        for (int k = 0; k < 64; ++k)
            acc = fmaf(__shfl(xv, k, 64), Wl[k][col], acc);
        Y[row * 64 + col] = acc;
    }
}

// B_r = rela@Wr ; C_q = rela[q_rel]@Wqr + Wqr_b.
__global__ void rel_precompute_kernel(const float* __restrict__ rela,
                                      const float* __restrict__ Wr,
                                      const float* __restrict__ Wqr,
                                      const float* __restrict__ Wqr_b,
                                      const int* __restrict__ q_rel,
                                      float* __restrict__ Br,
                                      float* __restrict__ Cq,
                                      int nrel, int nq) {
    __shared__ float W1[64][64];
    __shared__ float W2[64][64];
    int tid = threadIdx.x;
    for (int i = tid; i < 4096; i += 256) {
        W1[i >> 6][i & 63] = Wr[i];
        W2[i >> 6][i & 63] = Wqr[i];
    }
    __syncthreads();
    int col = tid & 63;
    int r4  = tid >> 6;
    int total = nrel + nq;
    for (int row = blockIdx.x * 4 + r4; row < total; row += gridDim.x * 4) {
        if (row < nrel) {
            float xv  = rela[(size_t)row * 64 + col];
            float acc = 0.0f;
#pragma unroll
            for (int k = 0; k < 64; ++k)
                acc = fmaf(__shfl(xv, k, 64), W1[k][col], acc);
            Br[(size_t)row * 64 + col] = acc;
        } else {
            int q  = row - nrel;
            int rr = q_rel[q];
            float xv  = rela[(size_t)rr * 64 + col];
            float acc = Wqr_b[col];
#pragma unroll
            for (int k = 0; k < 64; ++k)
                acc = fmaf(__shfl(xv, k, 64), W2[k][col], acc);
            Cq[(size_t)q * 64 + col] = acc;
        }
    }
}

// 4 edges per wave, 16 lanes x float4 per edge.
__global__ void edge_kernel(const int* __restrict__ edges,
                            const float* __restrict__ hidden,
                            const float* __restrict__ rela,
                            const float* __restrict__ hsWs,
                            const float* __restrict__ Br,
                            const float* __restrict__ Cq,
                            const float* __restrict__ w_alpha_w,
                            const float* __restrict__ w_alpha_b,
                            int* __restrict__ cnt,
                            int* __restrict__ slot,
                            int* __restrict__ obj_i,
                            float* __restrict__ out_alpha,
                            float* __restrict__ out_message,
                            float* __restrict__ out_obj,
                            float* __restrict__ out_alpha_temp,
                            int nedge) {
    int tid  = threadIdx.x;
    int lane = tid & 63;
    int g    = lane >> 4;        // edge slot in wave (0..3)
    int s    = lane & 15;        // feature chunk (4 floats each)
    long e0  = ((long)blockIdx.x * 4 + (tid >> 6)) * 4;
    if (e0 >= nedge) return;
    long e   = e0 + g;
    bool valid = (e < nedge);

    // 4 edges' metadata = 24 consecutive ints; coalesced load + broadcast.
    int md = 0;
    long mbase = e0 * 6;
    if (lane < 24 && (mbase + lane) < (long)nedge * 6) md = edges[mbase + lane];
    int r_idx = __shfl(md, g * 6 + 0, 64);
    int rel   = __shfl(md, g * 6 + 2, 64);
    int sub   = __shfl(md, g * 6 + 4, 64);
    int obj   = __shfl(md, g * 6 + 5, 64);
    if (!valid) { r_idx = 0; rel = 0; sub = 0; obj = 0; }

    const float4 h4 = *(const float4*)(hsWs + (size_t)sub  * 64 + s * 4);
    const float4 b4 = *(const float4*)(Br   + (size_t)rel  * 64 + s * 4);
    const float4 c4 = *(const float4*)(Cq   + (size_t)r_idx* 64 + s * 4);
    const float4 hv = *(const float4*)(hidden + (size_t)sub * 64 + s * 4);
    const float4 rv = *(const float4*)(rela   + (size_t)rel * 64 + s * 4);
    const float4 wa = *(const float4*)(w_alpha_w + s * 4);

    float4 a4;
    a4.x = fmaxf(h4.x + b4.x + c4.x, 0.0f);
    a4.y = fmaxf(h4.y + b4.y + c4.y, 0.0f);
    a4.z = fmaxf(h4.z + b4.z + c4.z, 0.0f);
    a4.w = fmaxf(h4.w + b4.w + c4.w, 0.0f);

    float part = a4.x * wa.x + a4.y * wa.y + a4.z * wa.z + a4.w * wa.w;
    part += __shfl_xor(part, 1, 64);
    part += __shfl_xor(part, 2, 64);
    part += __shfl_xor(part, 4, 64);
    part += __shfl_xor(part, 8, 64);

    float at    = part + w_alpha_b[0];
    float alpha = 1.0f / (1.0f + __expf(-at));

    float4 m4;
    m4.x = alpha * (hv.x + rv.x);
    m4.y = alpha * (hv.y + rv.y);
    m4.z = alpha * (hv.z + rv.z);
    m4.w = alpha * (hv.w + rv.w);

    if (valid) {
        nt_store4(out_message + e * 64 + s * 4, m4);
        if (s == 0) {
            slot[e]  = atomicAdd(&cnt[obj], 1);
            obj_i[e] = obj;
            out_alpha[e] = alpha;            // re-read by agg: keep cacheable
            NT_STORE(&out_obj[e], (float)obj);
            NT_STORE(&out_alpha_temp[e], at);
        }
    }
}

// ---- 3-pass exclusive scan over cnt[n] -> offs[n], chunk = 1024 ----

__global__ void scan_reduce_kernel(const int* __restrict__ cnt,
                                   int* __restrict__ bsum, int n) {
    int i = blockIdx.x * 1024 + threadIdx.x;
    int v = (i < n) ? cnt[i] : 0;
    int lane = threadIdx.x & 63, w = threadIdx.x >> 6;
#pragma unroll
    for (int m = 1; m < 64; m <<= 1) v += __shfl_xor(v, m, 64);
    __shared__ int ws[16];
    if (lane == 0) ws[w] = v;
    __syncthreads();
    if (threadIdx.x == 0) {
        int s = 0;
#pragma unroll
        for (int k = 0; k < 16; ++k) s += ws[k];
        bsum[blockIdx.x] = s;
    }
}

__global__ void scan_top_kernel(int* __restrict__ bsum, int nb) {
    int tid = threadIdx.x;
    int lane = tid & 63, w = tid >> 6;
    int v = (tid < nb) ? bsum[tid] : 0;
    int ins = v;
#pragma unroll
    for (int off = 1; off < 64; off <<= 1) {
        int t = __shfl_up(ins, off, 64);
        if (lane >= off) ins += t;
    }
    __shared__ int ws[16];
    __shared__ int wo[16];
    if (lane == 63) ws[w] = ins;
    __syncthreads();
    if (tid == 0) {
        int s = 0;
        for (int k = 0; k < 16; ++k) { wo[k] = s; s += ws[k]; }
    }
    __syncthreads();
    if (tid < nb) bsum[tid] = wo[w] + ins - v;   // exclusive
}

__global__ void scan_apply_kernel(const int* __restrict__ cnt,
                                  const int* __restrict__ boffs,
                                  int* __restrict__ offs, int n) {
    int i = blockIdx.x * 1024 + threadIdx.x;
    int lane = threadIdx.x & 63, w = threadIdx.x >> 6;
    int v = (i < n) ? cnt[i] : 0;
    int ins = v;
#pragma unroll
    for (int off = 1; off < 64; off <<= 1) {
        int t = __shfl_up(ins, off, 64);
        if (lane >= off) ins += t;
    }
    __shared__ int ws[16];
    __shared__ int wo[16];
    if (lane == 63) ws[w] = ins;
    __syncthreads();
    if (threadIdx.x == 0) {
        int s = 0;
        for (int k = 0; k < 16; ++k) { wo[k] = s; s += ws[k]; }
    }
    __syncthreads();
    if (i < n) offs[i] = boffs[blockIdx.x] + wo[w] + ins - v;
}

__global__ void scatter_kernel(const int* __restrict__ obj_i,
                               const int* __restrict__ slot,
                               const int* __restrict__ offs,
                               int* __restrict__ eidx, int nedge) {
    int e = blockIdx.x * 256 + threadIdx.x;
    if (e >= nedge) return;
    eidx[offs[obj_i[e]] + slot[e]] = e;
}

// Per-node wave: recompute msg rows, float4 x 4-edge groups, then @ W_h.
__global__ void agg_matmul_kernel(const float* __restrict__ alpha,
                                  const int* __restrict__ edges,
                                  const float* __restrict__ hidden,
                                  const float* __restrict__ rela,
                                  const int* __restrict__ eidx,
                                  const int* __restrict__ offs,
                                  const int* __restrict__ cnt,
                                  const float* __restrict__ Wh,
                                  float* __restrict__ hidden_new,
                                  int nnode) {
    __shared__ float Wl[64][64];
    int tid = threadIdx.x;
    for (int i = tid; i < 4096; i += 256) Wl[i >> 6][i & 63] = Wh[i];
    __syncthreads();
    int lane = tid & 63;
    int g    = lane >> 4;
    int s    = lane & 15;
    int wv   = tid >> 6;
    for (long node = (long)blockIdx.x * 4 + wv; node < nnode;
         node += (long)gridDim.x * 4) {
        int beg = offs[node];
        int num = cnt[node];
        float4 acc = make_float4(0.f, 0.f, 0.f, 0.f);
        for (int base = 0; base < num; base += 64) {
            int chunk = min(64, num - base);
            // phase 1: metadata for up to 64 edges, all lanes in parallel
            int sb = 0, rl = 0;
            float al = 0.0f;                 // lanes >= chunk contribute 0
            if (lane < chunk) {
                int el = eidx[beg + base + lane];
                sb = edges[(size_t)el * 6 + 4];
                rl = edges[(size_t)el * 6 + 2];
                al = alpha[el];
            }
            // phase 2: 4 edges per iteration (one per 16-lane group)
            for (int j0 = 0; j0 < chunk; j0 += 4) {
                int j = j0 + g;              // <= 63 always
                int   sbk = __shfl(sb, j, 64);
                int   rlk = __shfl(rl, j, 64);
                float alk = __shfl(al, j, 64);
                const float4 hv = *(const float4*)(hidden + (size_t)sbk * 64 + s * 4);
                const float4 rv = *(const float4*)(rela   + (size_t)rlk * 64 + s * 4);
                acc.x = fmaf(alk, hv.x + rv.x, acc.x);
                acc.y = fmaf(alk, hv.y + rv.y, acc.y);
                acc.z = fmaf(alk, hv.z + rv.z, acc.z);
                acc.w = fmaf(alk, hv.w + rv.w, acc.w);
            }
        }
        // reduce across the 4 groups (xor 16, 32); all lanes end identical
        acc.x += __shfl_xor(acc.x, 16, 64); acc.x += __shfl_xor(acc.x, 32, 64);
        acc.y += __shfl_xor(acc.y, 16, 64); acc.y += __shfl_xor(acc.y, 32, 64);
        acc.z += __shfl_xor(acc.z, 16, 64); acc.z += __shfl_xor(acc.z, 32, 64);
        acc.w += __shfl_xor(acc.w, 16, 64); acc.w += __shfl_xor(acc.w, 32, 64);
        // matvec: out[lane] = sum_k x_k * Wl[k][lane]; x_k in lane k>>2, comp k&3
        float outv = 0.0f;
#pragma unroll
        for (int k = 0; k < 64; ++k) {
            float xk;
            if      ((k & 3) == 0) xk = __shfl(acc.x, k >> 2, 64);
            else if ((k & 3) == 1) xk = __shfl(acc.y, k >> 2, 64);
            else if ((k & 3) == 2) xk = __shfl(acc.z, k >> 2, 64);
            else                   xk = __shfl(acc.w, k >> 2, 64);
            outv = fmaf(xk, Wl[k][lane], outv);
        }
        NT_STORE(&hidden_new[node * 64 + lane], outv);
    }
}

extern "C" void kernel_launch(void* const* d_in, const int* in_sizes, int n_in,
                              void* d_out, int out_size, void* d_ws, size_t ws_size,
                              hipStream_t stream) {
    const int*   q_rel     = (const int*)d_in[1];
    const float* hidden    = (const float*)d_in[2];
    const int*   edges     = (const int*)d_in[3];
    const float* rela      = (const float*)d_in[5];
    const float* Ws        = (const float*)d_in[6];
    const float* Wr        = (const float*)d_in[7];
    const float* Wqr       = (const float*)d_in[8];
    const float* Wqr_b     = (const float*)d_in[9];
    const float* w_alpha_w = (const float*)d_in[10];
    const float* w_alpha_b = (const float*)d_in[11];
    const float* W_h       = (const float*)d_in[12];

    const int n_node = in_sizes[2] / 64;    // 100000
    const int n_edge = in_sizes[3] / 6;     // 1000000
    const int n_rel  = in_sizes[5] / 64;    // 401
    const int n_q    = in_sizes[1];         // 256

    // Output layout (all fp32, return order).
    float* out            = (float*)d_out;
    float* out_hidden_new = out;
    float* out_alpha      = out + (size_t)n_node * 64;
    float* out_message    = out_alpha + n_edge;
    float* out_obj        = out_message + (size_t)n_edge * 64;
    float* out_alpha_temp = out_obj + n_edge;

    // Workspace layout (~38.6 MB).
    float* hsWs = (float*)d_ws;                            // n_node*64 f32
    float* Br   = hsWs + (size_t)n_node * 64;              // n_rel*64
    float* Cq   = Br + (size_t)n_rel * 64;                 // n_q*64
    int*   cnt  = (int*)(Cq + (size_t)n_q * 64);           // n_node
    int*   offs = cnt + n_node;                            // n_node
    int*   slot = offs + n_node;                           // n_edge
    int*   obj_i= slot + n_edge;                           // n_edge
    int*   eidx = obj_i + n_edge;                          // n_edge
    int*   bsum = eidx + n_edge;                           // ~128

    const int nb = (n_node + 1023) / 1024;                 // scan blocks (98)

    (void)hipMemsetAsync(cnt, 0, (size_t)n_node * sizeof(int), stream);

    // 1) hsWs = hidden @ Ws
    matmul64_kernel<<<2048, 256, 0, stream>>>(hidden, Ws, hsWs, n_node);

    // 2) B_r, C_q
    {
        int grid = (n_rel + n_q + 3) / 4;
        rel_precompute_kernel<<<grid, 256, 0, stream>>>(rela, Wr, Wqr, Wqr_b,
                                                        q_rel, Br, Cq, n_rel, n_q);
    }

    // 3) per-edge: attn, alpha, message (NT) + histogram(slot); 16 edges/block
    {
        int grid = (n_edge + 15) / 16;
        edge_kernel<<<grid, 256, 0, stream>>>(edges, hidden, rela, hsWs, Br, Cq,
                                              w_alpha_w, w_alpha_b,
                                              cnt, slot, obj_i,
                                              out_alpha, out_message, out_obj,
                                              out_alpha_temp, n_edge);
    }

    // 4) offs = exclusive_scan(cnt)
    scan_reduce_kernel<<<nb, 1024, 0, stream>>>(cnt, bsum, n_node);
    scan_top_kernel<<<1, 1024, 0, stream>>>(bsum, nb);
    scan_apply_kernel<<<nb, 1024, 0, stream>>>(cnt, bsum, offs, n_node);

    // 5) eidx CSR scatter
    scatter_kernel<<<(n_edge + 255) / 256, 256, 0, stream>>>(obj_i, slot, offs,
                                                             eidx, n_edge);

    // 6) hidden_new = segment_sum @ W_h, recomputed from L3-resident tables
    agg_matmul_kernel<<<4096, 256, 0, stream>>>(out_alpha, edges, hidden, rela,
                                                eidx, offs, cnt,
                                                W_h, out_hidden_new, n_node);
}